// Round 2
// baseline (351.892 us; speedup 1.0000x reference)
//
#include <hip/hip_runtime.h>
#include <cmath>

#define NB 32
#define NS 256
#define NT 64
#define START_TAG 62
#define STOP_TAG 63
#define G_SCALE 6.0f

// ws layout (floats): ws[b] = (path_score_b - gold_score_b) for each block b.

__global__ __launch_bounds__(256) void crf_forward(
    const float* __restrict__ feat, const int* __restrict__ targets,
    const int* __restrict__ lengths, float* __restrict__ ws) {
  const int b    = blockIdx.x;
  const int tid  = threadIdx.x;
  const int lane = tid & 63;
  const int q    = tid >> 6;      // wave id -> j-group [16q, 16q+16)
  const int jj   = lane & 15;
  const int ii   = lane >> 4;     // i-group [16ii, 16ii+16)
  const int j    = q * 16 + jj;
  const int i0   = ii * 16;

  __shared__ float s_v[2][NT];    // double-buffered score vector (exp domain)
  __shared__ float s_red[4];

  const float* fb = feat + (size_t)b * (NS * NT * NT);
  const int len = lengths[b];

  // ---- gold-path gather: issue early, consume in epilogue (off critical path)
  float gold = 0.0f;
  {
    int s = tid;                  // blockDim.x == NS == 256
    if (s < len) {
      int tgt = targets[b * NS + s];
      gold = fb[(size_t)s * (NT * NT) + tgt];
    }
  }

  // ---- init: v0 = exp(features[b,0,START,:])
  if (tid < NT) s_v[0][tid] = __expf(fb[START_TAG * NT + tid]);
  __syncthreads();

  float C = 0.0f;                 // accumulated log normalizer (lane-uniform)
  float E[16];                    // exp'd features for the current step
  float raw[4][16] = {};          // depth-4 prefetch ring (raw features)

  // prologue: prefetch steps 1..4, build E for step 1
  #pragma unroll
  for (int k = 0; k < 4; ++k) {
    int tt = 1 + k;
    if (tt < len) {
      const float* p = fb + (size_t)tt * (NT * NT) + i0 * NT + j;
      #pragma unroll
      for (int r = 0; r < 16; ++r) raw[k][r] = p[r * NT];
    }
  }
  #pragma unroll
  for (int r = 0; r < 16; ++r) E[r] = __expf(raw[0][r] - G_SCALE);

  int p = 0;                      // read parity
  for (int t = 1; t < len; t += 4) {
    #pragma unroll
    for (int k = 0; k < 4; ++k) {
      const int tt = t + k;
      if (tt >= len) break;       // block-uniform

      // -------- critical chain: read v, mat-vec partial, butterfly, write
      float vv[16];
      const float* vp = &s_v[p][i0];
      #pragma unroll
      for (int r = 0; r < 16; ++r) vv[r] = vp[r];

      float invm = 1.0f;
      if ((tt & 7) == 1) {        // renorm every 8 steps (uniform branch)
        float m = vv[0];
        #pragma unroll
        for (int r = 1; r < 16; ++r) m = fmaxf(m, vv[r]);
        m = fmaxf(m, __shfl_xor(m, 16));
        m = fmaxf(m, __shfl_xor(m, 32));
        invm = __builtin_amdgcn_rcpf(m);
        C += __logf(m);
      }

      float a0 = 0.f, a1 = 0.f, a2 = 0.f, a3 = 0.f;
      #pragma unroll
      for (int r = 0; r < 16; r += 4) {
        a0 = fmaf(E[r + 0], vv[r + 0], a0);
        a1 = fmaf(E[r + 1], vv[r + 1], a1);
        a2 = fmaf(E[r + 2], vv[r + 2], a2);
        a3 = fmaf(E[r + 3], vv[r + 3], a3);
      }
      float w = ((a0 + a1) + (a2 + a3)) * invm;
      w += __shfl_xor(w, 16);     // sum i-partials across ii groups
      w += __shfl_xor(w, 32);
      if (ii == 0) s_v[1 - p][j] = w;

      // -------- off-chain: exp for step tt+1, prefetch step tt+4
      #pragma unroll
      for (int r = 0; r < 16; ++r)
        E[r] = __expf(raw[(k + 1) & 3][r] - G_SCALE);
      if (tt + 4 < len) {
        const float* pp = fb + (size_t)(tt + 4) * (NT * NT) + i0 * NT + j;
        #pragma unroll
        for (int r = 0; r < 16; ++r) raw[k][r] = pp[r * NT];
      }

      __syncthreads();
      p ^= 1;
    }
  }

  // ---- epilogue: gold reduction + per-block result
  #pragma unroll
  for (int off = 32; off; off >>= 1) gold += __shfl_down(gold, off);
  if (lane == 0) s_red[q] = gold;
  __syncthreads();
  if (tid == 0) {
    float g = s_red[0] + s_red[1] + s_red[2] + s_red[3];
    float path = C + (float)(len - 1) * G_SCALE + __logf(s_v[p][STOP_TAG]);
    ws[b] = path - g;
  }
}

__global__ void finalize_kernel(const float* __restrict__ ws,
                                float* __restrict__ out) {
  int l = threadIdx.x;
  float v = (l < NB) ? ws[l] : 0.0f;
  #pragma unroll
  for (int off = 32; off; off >>= 1) v += __shfl_down(v, off);
  if (l == 0) out[0] = v * (1.0f / (float)NB);
}

extern "C" void kernel_launch(void* const* d_in, const int* in_sizes, int n_in,
                              void* d_out, int out_size, void* d_ws, size_t ws_size,
                              hipStream_t stream) {
  const float* feat    = (const float*)d_in[0];
  const int*   targets = (const int*)d_in[1];
  const int*   lengths = (const int*)d_in[2];
  float* ws  = (float*)d_ws;
  float* out = (float*)d_out;

  crf_forward<<<NB, 256, 0, stream>>>(feat, targets, lengths, ws);
  finalize_kernel<<<1, 64, 0, stream>>>(ws, out);
}

// Round 3
// 242.165 us; speedup vs baseline: 1.4531x; 1.4531x over previous
//
#include <hip/hip_runtime.h>
#include <cmath>

#define NB 32
#define NS 256
#define NT 64
#define START_TAG 62
#define STOP_TAG 63
#define CL 8                 // matrices per chunk
#define NCH 32               // max chunks per batch = ceil(255/8)
#define GS 8.0f              // exp shift: M = exp(f - GS), entries <= 1 w.h.p.
#define LOG64 4.1588830833596715f
#define LDP 68               // padded LDS row (floats) for At

// ws layout: [0, 8 MB): chunk products, bf16, (b*NCH+c)*4096 entries,
//            row j = column j of product P (i.e. P^T row-major).
//            then float res[33]: res[0..31] = path scores, res[32] = gold sum.
#define CMAT_BYTES ((size_t)NB * NCH * NT * NT * 2)

__device__ inline unsigned short f2bf(float x) {
  unsigned u = __float_as_uint(x);
  u += 0x7fffu + ((u >> 16) & 1u);   // RNE
  return (unsigned short)(u >> 16);
}

// ---------------- Phase 1: per-chunk matrix product ----------------
__global__ __launch_bounds__(256) void chunk_kernel(
    const float* __restrict__ feat, const int* __restrict__ lengths,
    unsigned int* __restrict__ cmat) {
  const int b = blockIdx.x;
  const int c = blockIdx.y;
  const int len = lengths[b];
  const int t1 = 1 + c * CL;
  const int nmat = min(len, t1 + CL) - t1;
  if (nmat <= 0) return;

  __shared__ float At[2][NT][LDP];   // running product, transposed
  __shared__ float Em[NT][NT];       // exp'd incoming matrix, row-major

  const int tid = threadIdx.x;
  const float* fb = feat + ((size_t)b * NS + t1) * (NT * NT);

  const int sj = tid & 15;           // staging: col quad
  const int sk = tid >> 4;           // staging: row base

  // stage matrix 0, exp'd, transposed into At[0]
  #pragma unroll
  for (int r = 0; r < 4; ++r) {
    const int row = sk + 16 * r;
    float4 f4 = *(const float4*)(fb + row * NT + 4 * sj);
    At[0][4 * sj + 0][row] = __expf(f4.x - GS);
    At[0][4 * sj + 1][row] = __expf(f4.y - GS);
    At[0][4 * sj + 2][row] = __expf(f4.z - GS);
    At[0][4 * sj + 3][row] = __expf(f4.w - GS);
  }

  float4 raw[4];
  if (nmat > 1) {
    #pragma unroll
    for (int r = 0; r < 4; ++r)
      raw[r] = *(const float4*)(fb + (size_t)(NT * NT) + (sk + 16 * r) * NT + 4 * sj);
  }
  __syncthreads();

  const int it = tid & 15;           // C tile rows [4it, 4it+4)
  const int jt = tid >> 4;           // C tile cols [4jt, 4jt+4)
  int p = 0;

  for (int k = 1; k < nmat; ++k) {
    // stage E = exp(raw - GS)
    #pragma unroll
    for (int r = 0; r < 4; ++r) {
      const int row = sk + 16 * r;
      float4 e4;
      e4.x = __expf(raw[r].x - GS);
      e4.y = __expf(raw[r].y - GS);
      e4.z = __expf(raw[r].z - GS);
      e4.w = __expf(raw[r].w - GS);
      *(float4*)&Em[row][4 * sj] = e4;
    }
    __syncthreads();

    // prefetch next matrix (in flight across the whole matmul)
    if (k + 1 < nmat) {
      #pragma unroll
      for (int r = 0; r < 4; ++r)
        raw[r] = *(const float4*)(fb + (size_t)(k + 1) * (NT * NT) +
                                  (sk + 16 * r) * NT + 4 * sj);
    }

    // C = A * M ; A[i][kk] = At[p][kk][i], M[kk][j] = Em[kk][j]
    float acc[4][4] = {};
    #pragma unroll 4
    for (int kk = 0; kk < NT; ++kk) {
      float4 a4 = *(const float4*)&At[p][kk][4 * it];
      float4 m4 = *(const float4*)&Em[kk][4 * jt];
      acc[0][0] = fmaf(a4.x, m4.x, acc[0][0]);
      acc[0][1] = fmaf(a4.x, m4.y, acc[0][1]);
      acc[0][2] = fmaf(a4.x, m4.z, acc[0][2]);
      acc[0][3] = fmaf(a4.x, m4.w, acc[0][3]);
      acc[1][0] = fmaf(a4.y, m4.x, acc[1][0]);
      acc[1][1] = fmaf(a4.y, m4.y, acc[1][1]);
      acc[1][2] = fmaf(a4.y, m4.z, acc[1][2]);
      acc[1][3] = fmaf(a4.y, m4.w, acc[1][3]);
      acc[2][0] = fmaf(a4.z, m4.x, acc[2][0]);
      acc[2][1] = fmaf(a4.z, m4.y, acc[2][1]);
      acc[2][2] = fmaf(a4.z, m4.z, acc[2][2]);
      acc[2][3] = fmaf(a4.z, m4.w, acc[2][3]);
      acc[3][0] = fmaf(a4.w, m4.x, acc[3][0]);
      acc[3][1] = fmaf(a4.w, m4.y, acc[3][1]);
      acc[3][2] = fmaf(a4.w, m4.z, acc[3][2]);
      acc[3][3] = fmaf(a4.w, m4.w, acc[3][3]);
    }

    // write C^T * (1/64) into At[1-p]
    #pragma unroll
    for (int cc = 0; cc < 4; ++cc) {
      float4 w;
      w.x = acc[0][cc] * 0.015625f;
      w.y = acc[1][cc] * 0.015625f;
      w.z = acc[2][cc] * 0.015625f;
      w.w = acc[3][cc] * 0.015625f;
      *(float4*)&At[1 - p][4 * jt + cc][4 * it] = w;
    }
    __syncthreads();
    p ^= 1;
  }

  // dump At[p] (= P^T) as bf16, coalesced
  const int row = tid >> 2;
  const int cg = tid & 3;
  unsigned int ub[8];
  #pragma unroll
  for (int u = 0; u < 8; ++u) {
    float v0 = At[p][row][16 * cg + 2 * u];
    float v1 = At[p][row][16 * cg + 2 * u + 1];
    ub[u] = (unsigned)f2bf(v0) | ((unsigned)f2bf(v1) << 16);
  }
  unsigned int* dst = cmat + ((size_t)b * NCH + c) * 2048 + row * 32 + cg * 8;
  *(uint4*)dst = make_uint4(ub[0], ub[1], ub[2], ub[3]);
  *((uint4*)dst + 1) = make_uint4(ub[4], ub[5], ub[6], ub[7]);
}

// ---------------- Phase 2: sequential combine, 1 wave/batch, no barriers ----
__global__ __launch_bounds__(64) void combine_kernel(
    const float* __restrict__ feat, const int* __restrict__ lengths,
    const unsigned int* __restrict__ cmat, float* __restrict__ res) {
  const int b = blockIdx.x;
  const int j = threadIdx.x;
  __shared__ float sv[NT];
  const int len = lengths[b];
  const float* f0 = feat + (size_t)b * NS * (NT * NT);

  float x = f0[START_TAG * NT + j];
  float m = x;
  #pragma unroll
  for (int off = 32; off; off >>= 1) m = fmaxf(m, __shfl_xor(m, off));
  float v = __expf(x - m);
  float L = m;

  const int nch = (len - 1 + CL - 1) / CL;
  uint4 Q0[8];
  if (nch > 0) {
    const uint4* P = (const uint4*)cmat + (size_t)b * NCH * 512 + j * 8;
    #pragma unroll
    for (int w = 0; w < 8; ++w) Q0[w] = P[w];
  }

  for (int c2 = 0; c2 < nch; ++c2) {
    sv[j] = v;
    __builtin_amdgcn_wave_barrier();

    uint4 Q1[8];
    if (c2 + 1 < nch) {
      const uint4* P = (const uint4*)cmat + ((size_t)b * NCH + c2 + 1) * 512 + j * 8;
      #pragma unroll
      for (int w = 0; w < 8; ++w) Q1[w] = P[w];
    }

    float acc = 0.f;
    const float4* svp = (const float4*)sv;
    #pragma unroll
    for (int w = 0; w < 8; ++w) {
      uint4 q = Q0[w];
      float4 s0 = svp[2 * w], s1 = svp[2 * w + 1];
      acc = fmaf(__uint_as_float(q.x << 16), s0.x, acc);
      acc = fmaf(__uint_as_float(q.x & 0xffff0000u), s0.y, acc);
      acc = fmaf(__uint_as_float(q.y << 16), s0.z, acc);
      acc = fmaf(__uint_as_float(q.y & 0xffff0000u), s0.w, acc);
      acc = fmaf(__uint_as_float(q.z << 16), s1.x, acc);
      acc = fmaf(__uint_as_float(q.z & 0xffff0000u), s1.y, acc);
      acc = fmaf(__uint_as_float(q.w << 16), s1.z, acc);
      acc = fmaf(__uint_as_float(q.w & 0xffff0000u), s1.w, acc);
    }
    __builtin_amdgcn_wave_barrier();   // all sv reads done before next write

    const int tt1 = 1 + c2 * CL;
    const int nmat = min(len, tt1 + CL) - tt1;
    L += (float)nmat * GS + (float)(nmat - 1) * LOG64;

    float mm = acc;
    #pragma unroll
    for (int off = 32; off; off >>= 1) mm = fmaxf(mm, __shfl_xor(mm, off));
    v = acc / mm;
    L += __logf(mm);

    #pragma unroll
    for (int w = 0; w < 8; ++w) Q0[w] = Q1[w];
  }

  float lv = __logf(v);
  float path = L + __shfl(lv, STOP_TAG);
  if (j == 0) res[b] = path;
}

// ---------------- Gold score + finalize ----------------
__global__ __launch_bounds__(256) void gold_kernel(
    const float* __restrict__ feat, const int* __restrict__ targets,
    const int* __restrict__ lengths, float* __restrict__ res) {
  int idx = blockIdx.x * 256 + threadIdx.x;
  int b = idx >> 8;
  int s = idx & 255;
  float v = 0.0f;
  if (s < lengths[b]) {
    int tgt = targets[idx];
    v = feat[(size_t)idx * (NT * NT) + tgt];
  }
  #pragma unroll
  for (int off = 32; off; off >>= 1) v += __shfl_down(v, off);
  if ((threadIdx.x & 63) == 0) atomicAdd(&res[NB], v);
}

__global__ void finalize_kernel(const float* __restrict__ res,
                                float* __restrict__ out) {
  int l = threadIdx.x;
  float v = (l < NB) ? res[l] : 0.f;
  #pragma unroll
  for (int off = 32; off; off >>= 1) v += __shfl_down(v, off);
  if (l == 0) out[0] = (v - res[NB]) * (1.0f / (float)NB);
}

extern "C" void kernel_launch(void* const* d_in, const int* in_sizes, int n_in,
                              void* d_out, int out_size, void* d_ws, size_t ws_size,
                              hipStream_t stream) {
  const float* feat    = (const float*)d_in[0];
  const int*   targets = (const int*)d_in[1];
  const int*   lengths = (const int*)d_in[2];
  unsigned int* cmat = (unsigned int*)d_ws;
  float* res = (float*)((char*)d_ws + CMAT_BYTES);
  float* out = (float*)d_out;

  hipMemsetAsync(res + NB, 0, sizeof(float), stream);   // gold slot
  gold_kernel<<<NB, 256, 0, stream>>>(feat, targets, lengths, res);
  chunk_kernel<<<dim3(NB, NCH), 256, 0, stream>>>(feat, lengths, cmat);
  combine_kernel<<<NB, 64, 0, stream>>>(feat, lengths, cmat, res);
  finalize_kernel<<<1, 64, 0, stream>>>(res, out);
}

// Round 4
// 240.868 us; speedup vs baseline: 1.4609x; 1.0054x over previous
//
#include <hip/hip_runtime.h>
#include <cmath>

#define NB 32
#define NS 256
#define NT 64
#define START_TAG 62
#define STOP_TAG 63
#define CL 8                 // matrices per chunk
#define NCH 32               // max chunks per batch
#define GS 8.0f              // M = exp(f - GS); entries <= ~0.03
#define LOG64 4.1588830833596715f
#define SP 66                // padded LDS row stride (halfwords)

typedef __attribute__((ext_vector_type(8))) short short8;
typedef __attribute__((ext_vector_type(4))) float float4v;

union FragU { unsigned u[4]; short8 s; };

__device__ inline unsigned short f2bf(float x) {
  unsigned u = __float_as_uint(x);
  u += 0x7fffu + ((u >> 16) & 1u);   // RNE
  return (unsigned short)(u >> 16);
}
__device__ inline unsigned pack2(float a, float b) {
  return (unsigned)f2bf(a) | ((unsigned)f2bf(b) << 16);
}

// ---------------- Phase 1: per-chunk matrix product via MFMA ----------------
__global__ __launch_bounds__(256) void chunk_kernel(
    const float* __restrict__ feat, const int* __restrict__ lengths,
    unsigned int* __restrict__ cmat) {
  const int b = blockIdx.x;
  const int c = blockIdx.y;
  const int len = lengths[b];
  const int t1 = 1 + c * CL;
  const int nmat = min(len, t1 + CL) - t1;
  if (nmat <= 0) return;

  __shared__ unsigned short Pb[2][NT * SP];  // running product P, row-major [m][k]
  __shared__ unsigned short Et[2][NT * SP];  // incoming E transposed: Et[n][k]=E[k][n]

  const int tid = threadIdx.x;
  const float* fb = feat + ((size_t)b * NS + t1) * (NT * NT);

  // ---- stage matrix 0 (exp'd) row-major into Pb[0]
  {
    const int cj = tid & 15, rk = tid >> 4;
    #pragma unroll
    for (int r = 0; r < 4; ++r) {
      const int row = rk + 16 * r;
      float4 f4 = *(const float4*)(fb + row * NT + 4 * cj);
      unsigned* dst = (unsigned*)&Pb[0][row * SP + 4 * cj];
      dst[0] = pack2(__expf(f4.x - GS), __expf(f4.y - GS));
      dst[1] = pack2(__expf(f4.z - GS), __expf(f4.w - GS));
    }
  }

  // staging map for Et: thread -> cols 4sj..+3, row pairs (2r0,2r0+1)(+32)
  const int sj = tid & 15, r0 = tid >> 4;
  float4 raw[2][4];
  if (nmat > 1) {
    const float* p = fb + (NT * NT);
    raw[1][0] = *(const float4*)(p + (2 * r0     ) * NT + 4 * sj);
    raw[1][1] = *(const float4*)(p + (2 * r0 +  1) * NT + 4 * sj);
    raw[1][2] = *(const float4*)(p + (2 * r0 + 32) * NT + 4 * sj);
    raw[1][3] = *(const float4*)(p + (2 * r0 + 33) * NT + 4 * sj);
  }
  __syncthreads();

  const int lane = tid & 63, wv = tid >> 6;
  const int ln = lane & 15, q = lane >> 4;
  const int m0 = 16 * wv;            // this wave's C tile-row
  int pp = 0;

  for (int k = 1; k < nmat; ++k) {
    const int pf = k & 1;
    // prefetch matrix k+1 (in flight across convert+matmul)
    if (k + 1 < nmat) {
      const float* p = fb + (size_t)(k + 1) * (NT * NT);
      raw[1 - pf][0] = *(const float4*)(p + (2 * r0     ) * NT + 4 * sj);
      raw[1 - pf][1] = *(const float4*)(p + (2 * r0 +  1) * NT + 4 * sj);
      raw[1 - pf][2] = *(const float4*)(p + (2 * r0 + 32) * NT + 4 * sj);
      raw[1 - pf][3] = *(const float4*)(p + (2 * r0 + 33) * NT + 4 * sj);
    }
    // convert raw[pf] -> Et[pf]: Et[j][i] = exp(f[i][j]-GS), packed i-pairs
    {
      unsigned short* et = Et[pf];
      const float* r0p = (const float*)&raw[pf][0];
      const float* r1p = (const float*)&raw[pf][1];
      const float* r2p = (const float*)&raw[pf][2];
      const float* r3p = (const float*)&raw[pf][3];
      #pragma unroll
      for (int cc = 0; cc < 4; ++cc) {
        const int j = 4 * sj + cc;
        *(unsigned*)&et[j * SP + 2 * r0] =
            pack2(__expf(r0p[cc] - GS), __expf(r1p[cc] - GS));
        *(unsigned*)&et[j * SP + 2 * r0 + 32] =
            pack2(__expf(r2p[cc] - GS), __expf(r3p[cc] - GS));
      }
    }
    __syncthreads();   // Et[pf] ready; prev iter's Pb writes visible

    // Pnew = Pold * E via 16x16x32 bf16 MFMA (4 col-tiles, K=64 = 2 steps)
    FragU a0, a1;
    const unsigned* ap = (const unsigned*)&Pb[pp][(m0 + ln) * SP];
    a0.u[0] = ap[4 * q + 0]; a0.u[1] = ap[4 * q + 1];
    a0.u[2] = ap[4 * q + 2]; a0.u[3] = ap[4 * q + 3];
    a1.u[0] = ap[16 + 4 * q + 0]; a1.u[1] = ap[16 + 4 * q + 1];
    a1.u[2] = ap[16 + 4 * q + 2]; a1.u[3] = ap[16 + 4 * q + 3];

    float4v acc[4];
    #pragma unroll
    for (int tc = 0; tc < 4; ++tc) {
      FragU b0, b1;
      const unsigned* bp = (const unsigned*)&Et[pf][(16 * tc + ln) * SP];
      b0.u[0] = bp[4 * q + 0]; b0.u[1] = bp[4 * q + 1];
      b0.u[2] = bp[4 * q + 2]; b0.u[3] = bp[4 * q + 3];
      b1.u[0] = bp[16 + 4 * q + 0]; b1.u[1] = bp[16 + 4 * q + 1];
      b1.u[2] = bp[16 + 4 * q + 2]; b1.u[3] = bp[16 + 4 * q + 3];
      float4v z = {0.f, 0.f, 0.f, 0.f};
      acc[tc] = __builtin_amdgcn_mfma_f32_16x16x32_bf16(a0.s, b0.s, z, 0, 0, 0);
      acc[tc] = __builtin_amdgcn_mfma_f32_16x16x32_bf16(a1.s, b1.s, acc[tc], 0, 0, 0);
    }

    // write C * (1/64) as bf16 into Pb[1-pp]
    // D layout: row = 4q + reg (within tile-row m0), col = 16tc + ln
    unsigned short* pn = Pb[1 - pp];
    #pragma unroll
    for (int tc = 0; tc < 4; ++tc) {
      #pragma unroll
      for (int rg = 0; rg < 4; ++rg) {
        const int row = m0 + 4 * q + rg;
        pn[row * SP + 16 * tc + ln] = f2bf(acc[tc][rg] * 0.015625f);
      }
    }
    pp ^= 1;
    // next iteration's barrier makes these writes visible before A-frag reads
  }
  __syncthreads();

  // ---- dump transposed: cmat row j = column j of P  (P^T row-major, bf16)
  {
    const int j = tid >> 2, cg = tid & 3;
    unsigned ub[8];
    #pragma unroll
    for (int u = 0; u < 8; ++u) {
      unsigned short lo = Pb[pp][(16 * cg + 2 * u    ) * SP + j];
      unsigned short hi = Pb[pp][(16 * cg + 2 * u + 1) * SP + j];
      ub[u] = (unsigned)lo | ((unsigned)hi << 16);
    }
    unsigned* dst = cmat + ((size_t)b * NCH + c) * 2048 + j * 32 + cg * 8;
    *(uint4*)dst       = make_uint4(ub[0], ub[1], ub[2], ub[3]);
    *((uint4*)dst + 1) = make_uint4(ub[4], ub[5], ub[6], ub[7]);
  }
}

// ---------------- Phase 2: sequential combine + gold + finalize -------------
__global__ __launch_bounds__(64) void combine_kernel(
    const float* __restrict__ feat, const int* __restrict__ targets,
    const int* __restrict__ lengths, const unsigned int* __restrict__ cmat,
    float* __restrict__ out) {
  const int b = blockIdx.x;
  const int j = threadIdx.x;
  __shared__ float sv[NT];
  const int len = lengths[b];
  const float* f0 = feat + (size_t)b * NS * (NT * NT);

  // gold gather for this batch (off critical path)
  float gold = 0.f;
  #pragma unroll
  for (int g = 0; g < 4; ++g) {
    const int s = j + 64 * g;
    if (s < len) {
      const int tgt = targets[b * NS + s];
      gold += f0[(size_t)s * (NT * NT) + tgt];
    }
  }

  float x = f0[START_TAG * NT + j];
  float m = x;
  #pragma unroll
  for (int off = 32; off; off >>= 1) m = fmaxf(m, __shfl_xor(m, off));
  float v = __expf(x - m);
  float L = m;

  const int nch = (len - 1 + CL - 1) / CL;
  uint4 Q0[8];
  if (nch > 0) {
    const uint4* P = (const uint4*)cmat + (size_t)b * NCH * 512 + j * 8;
    #pragma unroll
    for (int w = 0; w < 8; ++w) Q0[w] = P[w];
  }

  for (int c2 = 0; c2 < nch; ++c2) {
    sv[j] = v;
    __builtin_amdgcn_wave_barrier();

    uint4 Q1[8];
    if (c2 + 1 < nch) {
      const uint4* P = (const uint4*)cmat + ((size_t)b * NCH + c2 + 1) * 512 + j * 8;
      #pragma unroll
      for (int w = 0; w < 8; ++w) Q1[w] = P[w];
    }

    float acc = 0.f;
    const float4* svp = (const float4*)sv;
    #pragma unroll
    for (int w = 0; w < 8; ++w) {
      uint4 qq = Q0[w];
      float4 s0 = svp[2 * w], s1 = svp[2 * w + 1];
      acc = fmaf(__uint_as_float(qq.x << 16), s0.x, acc);
      acc = fmaf(__uint_as_float(qq.x & 0xffff0000u), s0.y, acc);
      acc = fmaf(__uint_as_float(qq.y << 16), s0.z, acc);
      acc = fmaf(__uint_as_float(qq.y & 0xffff0000u), s0.w, acc);
      acc = fmaf(__uint_as_float(qq.z << 16), s1.x, acc);
      acc = fmaf(__uint_as_float(qq.z & 0xffff0000u), s1.y, acc);
      acc = fmaf(__uint_as_float(qq.w << 16), s1.z, acc);
      acc = fmaf(__uint_as_float(qq.w & 0xffff0000u), s1.w, acc);
    }
    __builtin_amdgcn_wave_barrier();

    const int tt1 = 1 + c2 * CL;
    const int nmat = min(len, tt1 + CL) - tt1;
    L += (float)nmat * GS + (float)(nmat - 1) * LOG64;

    float mm = acc;
    #pragma unroll
    for (int off = 32; off; off >>= 1) mm = fmaxf(mm, __shfl_xor(mm, off));
    v = acc / mm;
    L += __logf(mm);

    #pragma unroll
    for (int w = 0; w < 8; ++w) Q0[w] = Q1[w];
  }

  float lv = __logf(v);
  float path = L + __shfl(lv, STOP_TAG);

  #pragma unroll
  for (int off = 32; off; off >>= 1) gold += __shfl_down(gold, off);
  if (j == 0) atomicAdd(out, (path - gold) * (1.0f / (float)NB));
}

extern "C" void kernel_launch(void* const* d_in, const int* in_sizes, int n_in,
                              void* d_out, int out_size, void* d_ws, size_t ws_size,
                              hipStream_t stream) {
  const float* feat    = (const float*)d_in[0];
  const int*   targets = (const int*)d_in[1];
  const int*   lengths = (const int*)d_in[2];
  unsigned int* cmat = (unsigned int*)d_ws;   // 8 MB of bf16 chunk products
  float* out = (float*)d_out;

  hipMemsetAsync(d_out, 0, sizeof(float), stream);
  chunk_kernel<<<dim3(NB, NCH), 256, 0, stream>>>(feat, lengths, cmat);
  combine_kernel<<<NB, 64, 0, stream>>>(feat, targets, lengths, cmat, out);
}

// Round 5
// 223.361 us; speedup vs baseline: 1.5754x; 1.0784x over previous
//
#include <hip/hip_runtime.h>
#include <cmath>

#define NB 32
#define NS 256
#define NT 64
#define START_TAG 62
#define STOP_TAG 63
#define CL 8                 // matrices per chunk
#define NCH 32               // chunks per batch
#define GS 8.0f              // M = exp(f - GS)
#define LOG64 4.1588830833596715f

typedef __attribute__((ext_vector_type(8))) short short8;
typedef __attribute__((ext_vector_type(4))) float float4v;

union FragU { unsigned u[4]; short8 s; unsigned short h[8]; };

__device__ inline unsigned pkbf(float a, float b) {
  // pack two floats as bf16 pair (round-half-up; bias negligible here)
  unsigned ua = (__float_as_uint(a) + 0x8000u) >> 16;
  unsigned ub = (__float_as_uint(b) + 0x8000u) & 0xffff0000u;
  return ua | ub;
}

// ---------------- Phase 1: wave-per-chunk matrix product, ZERO barriers -----
// Each wave owns one (batch, chunk): Q = (running product)^T kept in B-frag
// registers; per multiply: A = exp(feat - GS - ln64)^T streamed from global,
// D = A*B (MFMA), D repacked to next B via in-wave shuffles. No LDS, no
// __syncthreads -> no vmcnt(0) drains; prefetch stays in flight.
__global__ __launch_bounds__(256) void chunk_kernel(
    const float* __restrict__ feat, const int* __restrict__ lengths,
    unsigned short* __restrict__ cmat) {
  const int wv  = threadIdx.x >> 6;
  const int gid = blockIdx.x * 4 + wv;        // 0..1023
  const int b   = gid >> 5;                   // NCH = 32
  const int c   = gid & 31;
  const int len = lengths[b];
  const int t1  = 1 + c * CL;
  const int nmat = min(len, t1 + CL) - t1;
  if (nmat <= 0) return;

  const int lane = threadIdx.x & 63;
  const int q  = lane >> 4;
  const int cc = lane & 15;

  const float* fb = feat + ((size_t)b * NS + t1) * (NT * NT);

  // ---- init: BQ = E0^T in B-frag layout.
  // BQ[h][tj] elem j = Q[32h+8q+j][16tj+cc] = exp(fb[16tj+cc][32h+8q+j] - GS)
  FragU BQ[2][4];
  #pragma unroll
  for (int h = 0; h < 2; ++h)
    #pragma unroll
    for (int tj = 0; tj < 4; ++tj) {
      const float* p = fb + (16 * tj + cc) * NT + 32 * h + 8 * q;
      float4 x = *(const float4*)p;
      float4 y = *(const float4*)(p + 4);
      BQ[h][tj].u[0] = pkbf(__expf(x.x - GS), __expf(x.y - GS));
      BQ[h][tj].u[1] = pkbf(__expf(x.z - GS), __expf(x.w - GS));
      BQ[h][tj].u[2] = pkbf(__expf(y.x - GS), __expf(y.y - GS));
      BQ[h][tj].u[3] = pkbf(__expf(y.z - GS), __expf(y.w - GS));
    }

  // prefetch matrix t1+1 in A^T pattern: raw[mi][kh][j] = f[32kh+8q+j][16mi+cc]
  float raw[4][2][8];
  if (nmat > 1) {
    const float* p = fb + NT * NT;
    #pragma unroll
    for (int mi = 0; mi < 4; ++mi)
      #pragma unroll
      for (int kh = 0; kh < 2; ++kh)
        #pragma unroll
        for (int j = 0; j < 8; ++j)
          raw[mi][kh][j] = p[(32 * kh + 8 * q + j) * NT + 16 * mi + cc];
  }

  const int src0 = (((q & 1) * 2) << 4) | cc;
  const int src1 = src0 + 16;
  const bool hi = (q >> 1) != 0;

  for (int k = 1; k < nmat; ++k) {
    // convert raw -> FA (frees raw before next prefetch); 1/64 scale folded in
    FragU FA[4][2];
    #pragma unroll
    for (int mi = 0; mi < 4; ++mi)
      #pragma unroll
      for (int kh = 0; kh < 2; ++kh)
        #pragma unroll
        for (int j2 = 0; j2 < 4; ++j2)
          FA[mi][kh].u[j2] =
              pkbf(__expf(raw[mi][kh][2 * j2]     - (GS + LOG64)),
                   __expf(raw[mi][kh][2 * j2 + 1] - (GS + LOG64)));

    // prefetch matrix k+1 (in flight across MFMA + repack, no barrier ahead)
    if (k + 1 < nmat) {
      const float* p = fb + (size_t)(k + 1) * (NT * NT);
      #pragma unroll
      for (int mi = 0; mi < 4; ++mi)
        #pragma unroll
        for (int kh = 0; kh < 2; ++kh)
          #pragma unroll
          for (int j = 0; j < 8; ++j)
            raw[mi][kh][j] = p[(32 * kh + 8 * q + j) * NT + 16 * mi + cc];
    }

    // Q' = A * Q : 4x4 tiles of 16x16, K=64 via 2 chained MFMAs
    float4v acc[4][4];
    #pragma unroll
    for (int ti = 0; ti < 4; ++ti)
      #pragma unroll
      for (int tj = 0; tj < 4; ++tj) {
        float4v z = {0.f, 0.f, 0.f, 0.f};
        z = __builtin_amdgcn_mfma_f32_16x16x32_bf16(FA[ti][0].s, BQ[0][tj].s, z, 0, 0, 0);
        acc[ti][tj] = __builtin_amdgcn_mfma_f32_16x16x32_bf16(FA[ti][1].s, BQ[1][tj].s, z, 0, 0, 0);
      }

    // pack D reg pairs (rows 4q+{0,1} and 4q+{2,3} per tile, col cc)
    unsigned pk01[4][4], pk23[4][4];
    #pragma unroll
    for (int ti = 0; ti < 4; ++ti)
      #pragma unroll
      for (int tj = 0; tj < 4; ++tj) {
        pk01[ti][tj] = pkbf(acc[ti][tj][0], acc[ti][tj][1]);
        pk23[ti][tj] = pkbf(acc[ti][tj][2], acc[ti][tj][3]);
      }

    // repack D -> next BQ: BQ[h][tj] elem j = Q'[32h+8q+j][16tj+cc]
    // src lane = 16*(2(q&1)+(j>>2)) + cc ; tile ti' = 2h + (q>>1)
    #pragma unroll
    for (int h = 0; h < 2; ++h)
      #pragma unroll
      for (int tj = 0; tj < 4; ++tj) {
        unsigned a0 = (unsigned)__shfl((int)pk01[2 * h][tj],     src0);
        unsigned b0 = (unsigned)__shfl((int)pk01[2 * h + 1][tj], src0);
        unsigned a1 = (unsigned)__shfl((int)pk23[2 * h][tj],     src0);
        unsigned b1 = (unsigned)__shfl((int)pk23[2 * h + 1][tj], src0);
        unsigned a2 = (unsigned)__shfl((int)pk01[2 * h][tj],     src1);
        unsigned b2 = (unsigned)__shfl((int)pk01[2 * h + 1][tj], src1);
        unsigned a3 = (unsigned)__shfl((int)pk23[2 * h][tj],     src1);
        unsigned b3 = (unsigned)__shfl((int)pk23[2 * h + 1][tj], src1);
        BQ[h][tj].u[0] = hi ? b0 : a0;
        BQ[h][tj].u[1] = hi ? b1 : a1;
        BQ[h][tj].u[2] = hi ? b2 : a2;
        BQ[h][tj].u[3] = hi ? b3 : a3;
      }
  }

  // ---- store Q rows (= P^T row-major, bf16) — same cmat layout as before
  unsigned short* dst = cmat + ((size_t)b * NCH + c) * (NT * NT);
  #pragma unroll
  for (int h = 0; h < 2; ++h)
    #pragma unroll
    for (int tj = 0; tj < 4; ++tj)
      #pragma unroll
      for (int j = 0; j < 8; ++j)
        dst[(32 * h + 8 * q + j) * NT + 16 * tj + cc] = BQ[h][tj].h[j];
}

// ---------------- Phase 2: sequential combine + gold + finalize -------------
__global__ __launch_bounds__(64) void combine_kernel(
    const float* __restrict__ feat, const int* __restrict__ targets,
    const int* __restrict__ lengths, const unsigned int* __restrict__ cmat,
    float* __restrict__ out) {
  const int b = blockIdx.x;
  const int j = threadIdx.x;
  __shared__ float sv[NT];
  const int len = lengths[b];
  const float* f0 = feat + (size_t)b * NS * (NT * NT);

  float gold = 0.f;
  #pragma unroll
  for (int g = 0; g < 4; ++g) {
    const int s = j + 64 * g;
    if (s < len) {
      const int tgt = targets[b * NS + s];
      gold += f0[(size_t)s * (NT * NT) + tgt];
    }
  }

  float x = f0[START_TAG * NT + j];
  float m = x;
  #pragma unroll
  for (int off = 32; off; off >>= 1) m = fmaxf(m, __shfl_xor(m, off));
  float v = __expf(x - m);
  float L = m;

  const int nch = (len - 1 + CL - 1) / CL;
  uint4 Q0[8];
  if (nch > 0) {
    const uint4* P = (const uint4*)cmat + (size_t)b * NCH * 512 + j * 8;
    #pragma unroll
    for (int w = 0; w < 8; ++w) Q0[w] = P[w];
  }

  for (int c2 = 0; c2 < nch; ++c2) {
    sv[j] = v;
    __builtin_amdgcn_wave_barrier();

    uint4 Q1[8];
    if (c2 + 1 < nch) {
      const uint4* P = (const uint4*)cmat + ((size_t)b * NCH + c2 + 1) * 512 + j * 8;
      #pragma unroll
      for (int w = 0; w < 8; ++w) Q1[w] = P[w];
    }

    // 4 independent accumulator chains (was 1 chain of 64)
    float ac0 = 0.f, ac1 = 0.f, ac2 = 0.f, ac3 = 0.f;
    const float4* svp = (const float4*)sv;
    #pragma unroll
    for (int w = 0; w < 8; ++w) {
      uint4 qq = Q0[w];
      float4 s0 = svp[2 * w], s1 = svp[2 * w + 1];
      ac0 = fmaf(__uint_as_float(qq.x << 16), s0.x, ac0);
      ac1 = fmaf(__uint_as_float(qq.x & 0xffff0000u), s0.y, ac1);
      ac2 = fmaf(__uint_as_float(qq.y << 16), s0.z, ac2);
      ac3 = fmaf(__uint_as_float(qq.y & 0xffff0000u), s0.w, ac3);
      ac0 = fmaf(__uint_as_float(qq.z << 16), s1.x, ac0);
      ac1 = fmaf(__uint_as_float(qq.z & 0xffff0000u), s1.y, ac1);
      ac2 = fmaf(__uint_as_float(qq.w << 16), s1.z, ac2);
      ac3 = fmaf(__uint_as_float(qq.w & 0xffff0000u), s1.w, ac3);
    }
    float acc = (ac0 + ac1) + (ac2 + ac3);
    __builtin_amdgcn_wave_barrier();

    const int tt1 = 1 + c2 * CL;
    const int nmat = min(len, tt1 + CL) - tt1;
    L += (float)nmat * GS + (float)(nmat - 1) * LOG64;

    float mm = acc;
    #pragma unroll
    for (int off = 32; off; off >>= 1) mm = fmaxf(mm, __shfl_xor(mm, off));
    v = acc / mm;
    L += __logf(mm);

    #pragma unroll
    for (int w = 0; w < 8; ++w) Q0[w] = Q1[w];
  }

  float lv = __logf(v);
  float path = L + __shfl(lv, STOP_TAG);

  #pragma unroll
  for (int off = 32; off; off >>= 1) gold += __shfl_down(gold, off);
  if (j == 0) atomicAdd(out, (path - gold) * (1.0f / (float)NB));
}

extern "C" void kernel_launch(void* const* d_in, const int* in_sizes, int n_in,
                              void* d_out, int out_size, void* d_ws, size_t ws_size,
                              hipStream_t stream) {
  const float* feat    = (const float*)d_in[0];
  const int*   targets = (const int*)d_in[1];
  const int*   lengths = (const int*)d_in[2];
  unsigned short* cmat = (unsigned short*)d_ws;   // 8 MB bf16 chunk products
  float* out = (float*)d_out;

  hipMemsetAsync(d_out, 0, sizeof(float), stream);
  chunk_kernel<<<NB * NCH / 4, 256, 0, stream>>>(feat, lengths, cmat);
  combine_kernel<<<NB, 64, 0, stream>>>(feat, targets, lengths,
                                        (const unsigned int*)cmat, out);
}